// Round 1
// baseline (1888.143 us; speedup 1.0000x reference)
//
#include <hip/hip_runtime.h>
#include <math.h>

#define N_NODES 16384
#define DIM 128
#define HC 384          // HEADS * C
#define NEG_SLOPE 0.2f
#define KNN 16
#define KN_CAP 8

// ---------------- kernel 0: row squared norms ----------------
__global__ __launch_bounds__(256) void sq_kernel(const float* __restrict__ x,
                                                 float* __restrict__ sq) {
  const int wv = threadIdx.x >> 6;
  const int lane = threadIdx.x & 63;
  const int row = blockIdx.x * 4 + wv;
  const float2 v = *(const float2*)&x[row * DIM + lane * 2];
  float s = v.x * v.x + v.y * v.y;
  #pragma unroll
  for (int off = 32; off > 0; off >>= 1) s += __shfl_down(s, off);
  if (lane == 0) sq[row] = s;
}

// ---------------- kernel 1: xl = x@Wl, xr = x@Wr ----------------
// block 256 thr, BM=64, BN=128, micro 4x8, W transposed into LDS per K-half.
__global__ __launch_bounds__(256) void gemm_xw(const float* __restrict__ x,
                                               const float* __restrict__ Wl,
                                               const float* __restrict__ Wr,
                                               float* __restrict__ xl,
                                               float* __restrict__ xr) {
  __shared__ __align__(16) float As[64 * 132];
  __shared__ __align__(16) float WsT[128 * 68];
  const float* __restrict__ W = blockIdx.z ? Wr : Wl;
  float* __restrict__ o = blockIdx.z ? xr : xl;
  const int rowbase = blockIdx.x * 64;
  const int cb = blockIdx.y * 128;
  const int tid = threadIdx.x;
  const int tx = tid & 15, ty = tid >> 4;

  #pragma unroll
  for (int i = 0; i < 8; i++) {
    int f = i * 256 + tid;
    int r = f >> 5, k4 = f & 31;
    *(float4*)&As[r * 132 + k4 * 4] = *(const float4*)&x[(rowbase + r) * DIM + k4 * 4];
  }

  float acc[4][8];
  #pragma unroll
  for (int i = 0; i < 4; i++)
    #pragma unroll
    for (int j = 0; j < 8; j++) acc[i][j] = 0.f;

  for (int kh = 0; kh < 2; kh++) {
    __syncthreads();
    // stage W-half transposed: WsT[c][k], stride 68 (16B-aligned rows)
    #pragma unroll
    for (int i = 0; i < 8; i++) {
      int f = i * 256 + tid;
      int kk = f >> 5, cf4 = f & 31;
      float4 v = *(const float4*)&W[(kh * 64 + kk) * HC + cb + cf4 * 4];
      WsT[(cf4 * 4 + 0) * 68 + kk] = v.x;
      WsT[(cf4 * 4 + 1) * 68 + kk] = v.y;
      WsT[(cf4 * 4 + 2) * 68 + kk] = v.z;
      WsT[(cf4 * 4 + 3) * 68 + kk] = v.w;
    }
    __syncthreads();
    #pragma unroll
    for (int k4 = 0; k4 < 16; k4++) {
      float4 b[8];
      #pragma unroll
      for (int j = 0; j < 8; j++)
        b[j] = *(const float4*)&WsT[(tx + 16 * j) * 68 + k4 * 4];
      #pragma unroll
      for (int i = 0; i < 4; i++) {
        float4 a = *(const float4*)&As[(ty * 4 + i) * 132 + kh * 64 + k4 * 4];
        #pragma unroll
        for (int j = 0; j < 8; j++) {
          acc[i][j] += a.x * b[j].x;
          acc[i][j] += a.y * b[j].y;
          acc[i][j] += a.z * b[j].z;
          acc[i][j] += a.w * b[j].w;
        }
      }
    }
  }
  #pragma unroll
  for (int i = 0; i < 4; i++)
    #pragma unroll
    for (int j = 0; j < 8; j++)
      o[(rowbase + ty * 4 + i) * HC + cb + tx + 16 * j] = acc[i][j];
}

// ---------------- kernel 2: fused pairwise-dist + top-16 ----------------
// 512 thr (8 waves). BM=64 rows (full K staged), BN=256 cols/tile (K staged in halves).
// wave wv owns rows wv*8..wv*8+7; lane owns cols lane+64j. micro 8x4.
__global__ __launch_bounds__(512) void knn_kernel(const float* __restrict__ x,
                                                  const float* __restrict__ sq,
                                                  int* __restrict__ idxo) {
  __shared__ __align__(16) float As[64 * 132];
  __shared__ __align__(16) float Bs[256 * 68];
  __shared__ float Ss[256];
  __shared__ float Srow[64];
  __shared__ float Thr[64];
  __shared__ int Cnt[64];
  __shared__ float Topd[64][17];
  __shared__ int   Topi[64][17];
  __shared__ float Bufd[64][9];
  __shared__ int   Bufi[64][9];
  __shared__ int Flag;

  const int tid = threadIdx.x;
  const int lane = tid & 63;
  const int wv = tid >> 6;  // 0..7
  const int rowbase = blockIdx.x * 64;

  // stage A rows (full K), padded stride 132
  #pragma unroll
  for (int i = 0; i < 4; i++) {
    int f = i * 512 + tid;
    int r = f >> 5, k4 = f & 31;
    *(float4*)&As[r * 132 + k4 * 4] = *(const float4*)&x[(rowbase + r) * DIM + k4 * 4];
  }
  if (tid < 64) {
    Srow[tid] = sq[rowbase + tid];
    Thr[tid] = __builtin_inff();
    Cnt[tid] = 0;
  }
  if (tid == 0) Flag = 0;

  // persistent per-merge-thread (tid<64) top-k state
  int kcnt = 0, wj = 0, wpos = 0;
  float wd = __builtin_inff();

  for (int tile = 0; tile < N_NODES / 256; tile++) {
    const int colbase = tile * 256;
    float acc[8][4];
    #pragma unroll
    for (int i = 0; i < 8; i++)
      #pragma unroll
      for (int j = 0; j < 4; j++) acc[i][j] = 0.f;

    if (tid < 256) Ss[tid] = sq[colbase + tid];

    for (int kh = 0; kh < 2; kh++) {
      #pragma unroll
      for (int i = 0; i < 8; i++) {
        int f = i * 512 + tid;
        int c = f >> 4, k4 = f & 15;
        *(float4*)&Bs[c * 68 + k4 * 4] =
            *(const float4*)&x[(colbase + c) * DIM + kh * 64 + k4 * 4];
      }
      __syncthreads();
      const int koff = kh * 64;
      #pragma unroll
      for (int k4 = 0; k4 < 16; k4++) {
        float4 bb[4];
        #pragma unroll
        for (int j = 0; j < 4; j++)
          bb[j] = *(const float4*)&Bs[(lane + 64 * j) * 68 + k4 * 4];
        #pragma unroll
        for (int i = 0; i < 8; i++) {
          float4 aa = *(const float4*)&As[(wv * 8 + i) * 132 + koff + k4 * 4];
          #pragma unroll
          for (int j = 0; j < 4; j++) {
            acc[i][j] += aa.x * bb[j].x;
            acc[i][j] += aa.y * bb[j].y;
            acc[i][j] += aa.z * bb[j].z;
            acc[i][j] += aa.w * bb[j].w;
          }
        }
      }
      __syncthreads();
    }

    // distances (overwrite acc), mark candidates
    unsigned int pend = 0;
    #pragma unroll
    for (int i = 0; i < 8; i++) {
      const int r = wv * 8 + i;
      const int rg = rowbase + r;
      const float sr = Srow[r];
      #pragma unroll
      for (int j = 0; j < 4; j++) {
        const int cg = colbase + lane + 64 * j;
        float d = sr + Ss[lane + 64 * j] - 2.f * acc[i][j];
        acc[i][j] = d;
        if (cg != rg) pend |= (1u << (i * 4 + j));
      }
    }

    // push/merge rounds
    while (true) {
      #pragma unroll
      for (int i = 0; i < 8; i++) {
        const float t = Thr[wv * 8 + i];
        #pragma unroll
        for (int j = 0; j < 4; j++) {
          const unsigned int b = 1u << (i * 4 + j);
          if ((pend & b) && !(acc[i][j] <= t)) pend &= ~b;
        }
      }
      if (tid == 0) Flag = 0;
      __syncthreads();  // B1: reset visible before pushes
      if (pend) {
        #pragma unroll
        for (int i = 0; i < 8; i++) {
          #pragma unroll
          for (int j = 0; j < 4; j++) {
            const unsigned int b = 1u << (i * 4 + j);
            if (pend & b) {
              const int r = wv * 8 + i;
              const int slot = atomicAdd(&Cnt[r], 1);
              if (slot < KN_CAP) {
                Bufd[r][slot] = acc[i][j];
                Bufi[r][slot] = colbase + lane + 64 * j;
                pend &= ~b;
              }
            }
          }
        }
        if (pend) Flag = 1;  // capacity overflow -> retry round
      }
      __syncthreads();  // B2: pushes + flag visible
      const int fl = Flag;
      if (tid < 64) {
        int nn = Cnt[tid]; if (nn > KN_CAP) nn = KN_CAP;
        for (int e = 0; e < nn; e++) {
          const float d = Bufd[tid][e];
          const int jj = Bufi[tid][e];
          bool rescan = false;
          if (kcnt < KNN) {
            Topd[tid][kcnt] = d; Topi[tid][kcnt] = jj; kcnt++;
            rescan = (kcnt == KNN);
          } else if (d < wd || (d == wd && jj < wj)) {
            Topd[tid][wpos] = d; Topi[tid][wpos] = jj;
            rescan = true;
          }
          if (rescan) {  // recompute lexicographic-max (worst) of the 16
            wd = Topd[tid][0]; wj = Topi[tid][0]; wpos = 0;
            #pragma unroll
            for (int e2 = 1; e2 < KNN; e2++) {
              const float dd = Topd[tid][e2];
              const int j2 = Topi[tid][e2];
              if (dd > wd || (dd == wd && j2 > wj)) { wd = dd; wj = j2; wpos = e2; }
            }
            Thr[tid] = wd;
          }
        }
        Cnt[tid] = 0;
      }
      __syncthreads();  // B3: merge visible; orders fl-read vs next reset
      if (fl == 0) break;
    }
  }

  if (tid < 64) {
    #pragma unroll
    for (int e = 0; e < KNN; e++)
      idxo[(rowbase + tid) * KNN + e] = Topi[tid][e];
  }
}

// ---------------- kernel 3: GATv2 attention epilogue ----------------
// one wave per node; lane owns channels (lane, lane+64) per head.
__global__ __launch_bounds__(64) void attn_kernel(const float* __restrict__ xl,
                                                  const float* __restrict__ xr,
                                                  const float* __restrict__ att,
                                                  const float* __restrict__ bias,
                                                  const int* __restrict__ idxo,
                                                  float* __restrict__ out) {
  const int n = blockIdx.x;
  const int lane = threadIdx.x;
  __shared__ int nb[KNN];
  if (lane < KNN) nb[lane] = idxo[n * KNN + lane];
  __syncthreads();
  float o0 = 0.f, o1 = 0.f;
  #pragma unroll
  for (int h = 0; h < 3; h++) {
    const float r0 = xr[n * HC + h * 128 + lane];
    const float r1 = xr[n * HC + h * 128 + 64 + lane];
    const float a0 = att[h * 128 + lane];
    const float a1 = att[h * 128 + 64 + lane];
    float v0[KNN], v1[KNN], e[KNN];
    #pragma unroll
    for (int kk = 0; kk < KNN; kk++) {
      const float* xp = &xl[(size_t)nb[kk] * HC + h * 128];
      float x0 = xp[lane], x1 = xp[64 + lane];
      v0[kk] = x0; v1[kk] = x1;
      float g0 = x0 + r0; g0 = g0 >= 0.f ? g0 : NEG_SLOPE * g0;
      float g1 = x1 + r1; g1 = g1 >= 0.f ? g1 : NEG_SLOPE * g1;
      float p = a0 * g0 + a1 * g1;
      #pragma unroll
      for (int off = 32; off > 0; off >>= 1) p += __shfl_xor(p, off);
      e[kk] = p;
    }
    float m = e[0];
    #pragma unroll
    for (int kk = 1; kk < KNN; kk++) m = fmaxf(m, e[kk]);
    float s = 0.f;
    float w[KNN];
    #pragma unroll
    for (int kk = 0; kk < KNN; kk++) { w[kk] = expf(e[kk] - m); s += w[kk]; }
    #pragma unroll
    for (int kk = 0; kk < KNN; kk++) {
      float al = w[kk] / s;
      o0 += al * v0[kk];
      o1 += al * v1[kk];
    }
  }
  out[n * 128 + lane]      = o0 / 3.f + bias[lane];
  out[n * 128 + 64 + lane] = o1 / 3.f + bias[64 + lane];
}

extern "C" void kernel_launch(void* const* d_in, const int* in_sizes, int n_in,
                              void* d_out, int out_size, void* d_ws, size_t ws_size,
                              hipStream_t stream) {
  const float* x    = (const float*)d_in[0];
  const float* Wl   = (const float*)d_in[1];
  const float* Wr   = (const float*)d_in[2];
  const float* att  = (const float*)d_in[3];
  const float* bias = (const float*)d_in[4];
  float* out = (float*)d_out;

  float* xl  = (float*)d_ws;                       // N x 384
  float* xr  = xl + (size_t)N_NODES * HC;          // N x 384
  float* sqv = xr + (size_t)N_NODES * HC;          // N
  int*   idx = (int*)(sqv + N_NODES);              // N x 16

  sq_kernel<<<N_NODES / 4, 256, 0, stream>>>(x, sqv);
  gemm_xw<<<dim3(N_NODES / 64, 3, 2), 256, 0, stream>>>(x, Wl, Wr, xl, xr);
  knn_kernel<<<N_NODES / 64, 512, 0, stream>>>(x, sqv, idx);
  attn_kernel<<<N_NODES, 64, 0, stream>>>(xl, xr, att, bias, idx, out);
}